// Round 9
// baseline (845.345 us; speedup 1.0000x reference)
//
#include <hip/hip_runtime.h>
#include <math.h>

#define NNODES 50000
#define NEDGES 800000
#define NGRAPHS 500
#define NEG_SLOPE 0.2f
#define BN_EPS 1e-5f
#define NRANGE 196            // ceil(50000/256) node ranges of 256
#define RH_EPB 4096           // edges per block in range hist/reorder
#define RH_NB ((NEDGES + RH_EPB - 1) / RH_EPB)
#define MAXRE 5120            // LDS stage capacity per range

typedef unsigned int uint;
typedef unsigned short ushort;
typedef __attribute__((ext_vector_type(8))) short bf16x8;
typedef __attribute__((ext_vector_type(4))) float f32x4;

// ---- bf16 helpers (storage-only bf16; math fp32 / MFMA fp32-acc) ----
__device__ __forceinline__ float bf2f(ushort u) { return __uint_as_float(((uint)u) << 16); }
__device__ __forceinline__ float bflo(uint u)   { return __uint_as_float(u << 16); }
__device__ __forceinline__ float bfhi(uint u)   { return __uint_as_float(u & 0xffff0000u); }
__device__ __forceinline__ ushort f2bf(float f) {
    uint u = __float_as_uint(f);
    u = (u + 0x7fffu + ((u >> 16) & 1u)) >> 16;   // RNE
    return (ushort)u;
}

// ---- prep: zero rhist + BN accumulators, convert/transpose weights to bf16 ----
__global__ void prep_kernel(const float* __restrict__ W0, const float* __restrict__ W1,
                            const float* __restrict__ W2, ushort* __restrict__ Wt0,
                            ushort* __restrict__ Wt1, ushort* __restrict__ Wt2,
                            int* __restrict__ rhist, float* __restrict__ bnacc) {
    int t = blockIdx.x * 256 + threadIdx.x;
    if (blockIdx.x == 0 && threadIdx.x < NRANGE) rhist[threadIdx.x] = 0;
    if (blockIdx.x == 1) {   // zero gsumA/gsumsqA/gsumB/gsumsqB (4*128 floats)
        bnacc[threadIdx.x] = 0.f;
        bnacc[256 + threadIdx.x] = 0.f;
    }
    if (t < 16384) {                       // W0 [128][128]
        int k = t >> 7, m = t & 127;
        Wt0[m * 128 + k] = f2bf(W0[t]);
    } else if (t < 32768) {                // W1 [128][128]
        int i = t - 16384;
        int k = i >> 7, m = i & 127;
        Wt1[m * 128 + k] = f2bf(W1[i]);
    } else if (t < 36864) {                // W2 [128][32]
        int i = t - 32768;
        int k = i >> 5, m = i & 31;
        Wt2[m * 128 + k] = f2bf(W2[i]);
    }
}

// ==================== bucketed CSR build ====================
__global__ void range_hist_kernel(const int* __restrict__ dst, int* __restrict__ rhist) {
    __shared__ int cnt[NRANGE];
    for (int i = threadIdx.x; i < NRANGE; i += 256) cnt[i] = 0;
    __syncthreads();
    int base = blockIdx.x * RH_EPB;
    int end = base + RH_EPB; if (end > NEDGES) end = NEDGES;
    for (int i = base + threadIdx.x; i < end; i += 256) atomicAdd(&cnt[dst[i] >> 8], 1);
    __syncthreads();
    for (int i = threadIdx.x; i < NRANGE; i += 256)
        if (cnt[i]) atomicAdd(&rhist[i], cnt[i]);
}

__global__ void range_scan_kernel(const int* __restrict__ rhist, int* __restrict__ rbase,
                                  int* __restrict__ rcursor, int* __restrict__ rowptr) {
    __shared__ int ls[256];
    int t = threadIdx.x;
    ls[t] = (t < NRANGE) ? rhist[t] : 0;
    __syncthreads();
    for (int off = 1; off < 256; off <<= 1) {
        int u = (t >= off) ? ls[t - off] : 0;
        __syncthreads();
        ls[t] += u;
        __syncthreads();
    }
    if (t < NRANGE) {
        int b = (t == 0) ? 0 : ls[t - 1];
        rbase[t] = b;
        rcursor[t] = b;
    }
    if (t == 0) { rbase[NRANGE] = NEDGES; rowptr[NNODES] = NEDGES; }
}

__global__ void reorder_kernel(const int* __restrict__ src, const int* __restrict__ dst,
                               int* __restrict__ rcursor, uint* __restrict__ bucket) {
    __shared__ int cnt[NRANGE];
    __shared__ int bofs[NRANGE];
    for (int i = threadIdx.x; i < NRANGE; i += 256) cnt[i] = 0;
    __syncthreads();
    int base = blockIdx.x * RH_EPB;
    int end = base + RH_EPB; if (end > NEDGES) end = NEDGES;
    for (int i = base + threadIdx.x; i < end; i += 256) atomicAdd(&cnt[dst[i] >> 8], 1);
    __syncthreads();
    for (int i = threadIdx.x; i < NRANGE; i += 256) {
        int c = cnt[i];
        bofs[i] = c ? atomicAdd(&rcursor[i], c) : 0;
    }
    __syncthreads();
    for (int i = threadIdx.x; i < NRANGE; i += 256) cnt[i] = 0;
    __syncthreads();
    for (int i = base + threadIdx.x; i < end; i += 256) {
        int d = dst[i], r = d >> 8;
        int loc = atomicAdd(&cnt[r], 1);
        bucket[bofs[r] + loc] = (uint)src[i] | ((uint)(d & 255) << 16);
    }
}

__global__ __launch_bounds__(256) void range_csr_kernel(const int* __restrict__ rbase,
                                                        const uint* __restrict__ bucket,
                                                        int* __restrict__ rowptr,
                                                        int* __restrict__ csr_src) {
    __shared__ uint ebuf[MAXRE];
    __shared__ int deg[256], excl[256], cur[256];
    const int r = blockIdx.x;
    const int b0 = rbase[r];
    const int cnt = rbase[r + 1] - b0;
    const int t = threadIdx.x;
    deg[t] = 0; cur[t] = 0;
    __syncthreads();
    for (int i = t; i < cnt; i += 256) {
        uint e = bucket[b0 + i];
        ebuf[i] = e;
        atomicAdd(&deg[e >> 16], 1);
    }
    __syncthreads();
    excl[t] = deg[t];
    __syncthreads();
    for (int off = 1; off < 256; off <<= 1) {
        int u = (t >= off) ? excl[t - off] : 0;
        __syncthreads();
        excl[t] += u;
        __syncthreads();
    }
    int myExcl = (t == 0) ? 0 : excl[t - 1];
    __syncthreads();
    excl[t] = myExcl;
    __syncthreads();
    int node = r * 256 + t;
    if (node < NNODES) rowptr[node] = b0 + myExcl;
    for (int i = t; i < cnt; i += 256) {
        uint e = ebuf[i];
        int dl = e >> 16;
        int loc = atomicAdd(&cur[dl], 1);
        csr_src[b0 + excl[dl] + loc] = (int)(e & 0xffffu);
    }
}

// ==================== MFMA bf16 GEMM, fused BN/ReLU input + el/er epilogue ====================
template <int M, bool HASBN>
__global__ __launch_bounds__(256) void gemm_mfma_kernel(
        const void* __restrict__ Xv, const ushort* __restrict__ Wt,
        const float* __restrict__ gsum, const float* __restrict__ gsumsq,
        const float* __restrict__ g, const float* __restrict__ beta,
        const float* __restrict__ al, const float* __restrict__ ar,
        ushort* __restrict__ Y, float* __restrict__ el, float* __restrict__ er, int N) {
    constexpr int H   = M / 32;
    constexpr int BR  = (M == 128) ? 64 : 128;
    constexpr int RT  = (M == 128) ? 4 : 2;
    constexpr int CT  = 2;
    constexpr int LDK = 136;
    __shared__ ushort xs[BR][LDK];
    __shared__ ushort ws[M][LDK];
    __shared__ float scs[128], shs[128];

    const int tid = threadIdx.x, wv = tid >> 6, lane = tid & 63;
    const int rowBase = blockIdx.x * BR;

    if (HASBN) {
        if (tid < 128) {
            const float inv = 1.f / NNODES;
            float mu  = gsum[tid] * inv;
            float var = gsumsq[tid] * inv - mu * mu;
            float sc  = g[tid] * rsqrtf(var + BN_EPS);
            scs[tid] = sc;
            shs[tid] = beta[tid] - mu * sc;
        }
        __syncthreads();
    }

    if (HASBN) {
        const ushort* X = (const ushort*)Xv;
        for (int i = tid; i < BR * 16; i += 256) {
            int rr = i >> 4, q = i & 15;
            int gr = rowBase + rr;
            uint4 u = make_uint4(0, 0, 0, 0);
            if (gr < N) u = *(const uint4*)(X + (size_t)gr * 128 + q * 8);
            uint arr[4] = {u.x, u.y, u.z, u.w};
            ushort* o = &xs[rr][q * 8];
#pragma unroll
            for (int j = 0; j < 4; ++j) {
                int c = q * 8 + j * 2;
                float lo = fmaxf(bflo(arr[j]) * scs[c] + shs[c], 0.f);
                float hi = fmaxf(bfhi(arr[j]) * scs[c + 1] + shs[c + 1], 0.f);
                o[j * 2]     = f2bf(lo);
                o[j * 2 + 1] = f2bf(hi);
            }
        }
    } else {
        const float* X = (const float*)Xv;
        for (int i = tid; i < BR * 32; i += 256) {
            int rr = i >> 5, c4 = i & 31;
            int gr = rowBase + rr;
            float4 v = make_float4(0.f, 0.f, 0.f, 0.f);
            if (gr < N) v = *(const float4*)(X + (size_t)gr * 128 + c4 * 4);
            ushort* o = &xs[rr][c4 * 4];
            o[0] = f2bf(v.x); o[1] = f2bf(v.y); o[2] = f2bf(v.z); o[3] = f2bf(v.w);
        }
    }
    for (int i = tid; i < M * 16; i += 256) {
        int rr = i >> 4, kc = (i & 15) * 8;
        *(uint4*)&ws[rr][kc] = *(const uint4*)(Wt + rr * 128 + kc);
    }
    __syncthreads();

    const int waveRow = (M == 128) ? 0 : (wv * 32);
    const int waveCol = (M == 128) ? (wv * 32) : 0;
    const int fr = lane & 15, quad = lane >> 4;

    f32x4 acc[RT][CT];
#pragma unroll
    for (int rt = 0; rt < RT; ++rt)
#pragma unroll
        for (int ct = 0; ct < CT; ++ct) acc[rt][ct] = (f32x4){0.f, 0.f, 0.f, 0.f};

#pragma unroll
    for (int ks = 0; ks < 4; ++ks) {
        const int kb = ks * 32 + quad * 8;
        bf16x8 a[RT], b[CT];
#pragma unroll
        for (int rt = 0; rt < RT; ++rt) a[rt] = *(const bf16x8*)&xs[waveRow + rt * 16 + fr][kb];
#pragma unroll
        for (int ct = 0; ct < CT; ++ct) b[ct] = *(const bf16x8*)&ws[waveCol + ct * 16 + fr][kb];
#pragma unroll
        for (int rt = 0; rt < RT; ++rt)
#pragma unroll
            for (int ct = 0; ct < CT; ++ct)
                acc[rt][ct] = __builtin_amdgcn_mfma_f32_16x16x32_bf16(a[rt], b[ct], acc[rt][ct], 0, 0, 0);
    }

#pragma unroll
    for (int rt = 0; rt < RT; ++rt)
#pragma unroll
        for (int ct = 0; ct < CT; ++ct)
#pragma unroll
            for (int rg = 0; rg < 4; ++rg) {
                int gr = rowBase + waveRow + rt * 16 + quad * 4 + rg;
                int gc = waveCol + ct * 16 + fr;
                if (gr < N) Y[(size_t)gr * M + gc] = f2bf(acc[rt][ct][rg]);
            }

    // fused el/er epilogue
    const float a0 = al[waveCol + fr],      a1 = al[waveCol + 16 + fr];
    const float g0 = ar[waveCol + fr],      g1 = ar[waveCol + 16 + fr];
    const int h = (M == 128) ? wv : 0;
#pragma unroll
    for (int rt = 0; rt < RT; ++rt)
#pragma unroll
        for (int rg = 0; rg < 4; ++rg) {
            float pe = acc[rt][0][rg] * a0 + acc[rt][1][rg] * a1;
            float pr = acc[rt][0][rg] * g0 + acc[rt][1][rg] * g1;
#pragma unroll
            for (int off = 1; off < 16; off <<= 1) {
                pe += __shfl_xor(pe, off);
                pr += __shfl_xor(pr, off);
            }
            int grow = rowBase + waveRow + rt * 16 + quad * 4 + rg;
            if (fr == 0 && grow < N) {
                el[grow * H + h] = pe;
                er[grow * H + h] = pr;
            }
        }
}

// ==================== gather H=4: ONE node per wave (TLP is king), bf16 out, fused BN ====================
__global__ __launch_bounds__(256) void gat_gather4_kernel(
        const int* __restrict__ rowptr, const int* __restrict__ csr_src,
        const float* __restrict__ el, const float* __restrict__ er,
        const ushort* __restrict__ feat, const float* __restrict__ bias,
        ushort* __restrict__ xnext, float* __restrict__ gsum, float* __restrict__ gsumsq) {
    const int wv = threadIdx.x >> 6, lane = threadIdx.x & 63;
    const int d = blockIdx.x * 4 + wv;
    const int h   = lane >> 4;
    const int k   = lane & 15;
    const int grp = lane & 48;
    const int c0  = lane * 2;
    float s0 = 0.f, s1 = 0.f, ss0 = 0.f, ss1 = 0.f;

    if (d < NNODES) {
        const int r0 = rowptr[d];
        const int deg = rowptr[d + 1] - r0;
        const float erh = er[d * 4 + h];
        float dnm = 0.f, ax = 0.f, ay = 0.f;

        for (int j0 = 0; j0 < deg; j0 += 16) {
            int eidx = j0 + k;
            int s_e = 0;
            float ex = 0.f;
            if (eidx < deg) {
                s_e = csr_src[r0 + eidx];
                float v = el[s_e * 4 + h] + erh;
                v = v > 0.f ? v : NEG_SLOPE * v;
                ex = __expf(v);
            }
            dnm += ex;
            uint u[16];
#pragma unroll
            for (int jj = 0; jj < 16; ++jj) {
                int sj = __builtin_amdgcn_readlane(s_e, jj);
                u[jj] = *(const uint*)(feat + (size_t)sj * 128 + c0);
            }
#pragma unroll
            for (int jj = 0; jj < 16; ++jj) {
                float exj = __shfl(ex, grp + jj);
                ax = fmaf(exj, bflo(u[jj]), ax);
                ay = fmaf(exj, bfhi(u[jj]), ay);
            }
        }
#pragma unroll
        for (int off = 1; off < 16; off <<= 1) dnm += __shfl_xor(dnm, off);
        float inv = (dnm > 0.f) ? 1.f / dnm : 0.f;
        float vx = ax * inv + bias[c0];
        float vy = ay * inv + bias[c0 + 1];
        uint pk = ((uint)f2bf(vy) << 16) | (uint)f2bf(vx);
        *(uint*)(xnext + (size_t)d * 128 + c0) = pk;
        s0 = vx; ss0 = vx * vx;
        s1 = vy; ss1 = vy * vy;
    }

    // cross-wave BN partial reduce + one atomic set per block (12500 chains/addr, staggered)
    __shared__ float reds[4][128], redss[4][128];
    reds[wv][c0] = s0;  reds[wv][c0 + 1] = s1;
    redss[wv][c0] = ss0; redss[wv][c0 + 1] = ss1;
    __syncthreads();
    int t = threadIdx.x;
    if (t < 128) {
        atomicAdd(&gsum[t], reds[0][t] + reds[1][t] + reds[2][t] + reds[3][t]);
    } else {
        int c = t - 128;
        atomicAdd(&gsumsq[c], redss[0][c] + redss[1][c] + redss[2][c] + redss[3][c]);
    }
}

// ==================== gather H=1 with fused graph pooling ====================
__global__ void gat_gather1_kernel(const int* __restrict__ rowptr, const int* __restrict__ csr_src,
                                   const float* __restrict__ el, const float* __restrict__ er,
                                   const ushort* __restrict__ feat, const float* __restrict__ bias,
                                   const int* __restrict__ gid, float* __restrict__ pooled) {
    int wave = (blockIdx.x * blockDim.x + threadIdx.x) >> 6;
    int lane = threadIdx.x & 63;
    if (wave >= NNODES) return;
    const int d = wave;
    const int r0 = rowptr[d];
    const int deg = rowptr[d + 1] - r0;
    const int half = lane >> 5;
    const int c    = lane & 31;
    const float erh = er[d];
    float dnm = 0.f, acc = 0.f;

    for (int j0 = 0; j0 < deg; j0 += 32) {
        int eidx = j0 + (lane & 31);
        int s_e = 0;
        float ex = 0.f;
        if (eidx < deg) {
            s_e = csr_src[r0 + eidx];
            float v = el[s_e] + erh;
            v = v > 0.f ? v : NEG_SLOPE * v;
            ex = __expf(v);
        }
        dnm += ex;
        ushort u[16];
#pragma unroll
        for (int jj = 0; jj < 16; ++jj) {
            int sj = __shfl(s_e, 2 * jj + half);
            u[jj] = feat[(size_t)sj * 32 + c];
        }
#pragma unroll
        for (int jj = 0; jj < 16; ++jj) {
            float exj = __shfl(ex, 2 * jj + half);
            acc = fmaf(exj, bf2f(u[jj]), acc);
        }
    }
#pragma unroll
    for (int off = 1; off < 32; off <<= 1) dnm += __shfl_xor(dnm, off);
    acc += __shfl_down(acc, 32);
    if (half == 0) {
        float inv = (dnm > 0.f) ? 1.f / dnm : 0.f;
        atomicAdd(&pooled[gid[d] * 32 + c], acc * inv + bias[c]);
    }
}

// ---- classifier ----
__global__ void classify_kernel(const float* __restrict__ pooled, const float* __restrict__ Wc,
                                const float* __restrict__ bc, float* __restrict__ out) {
    int t = blockIdx.x * blockDim.x + threadIdx.x;
    if (t >= NGRAPHS * 10) return;
    int gIdx = t / 10, j = t % 10;
    float s = bc[j];
#pragma unroll
    for (int c = 0; c < 32; ++c) s += pooled[gIdx * 32 + c] * Wc[c * 10 + j];
    out[t] = s;
}

extern "C" void kernel_launch(void* const* d_in, const int* in_sizes, int n_in,
                              void* d_out, int out_size, void* d_ws, size_t ws_size,
                              hipStream_t stream) {
    const float* x     = (const float*)d_in[0];
    const int*   esrc  = (const int*)d_in[1];
    const int*   edst  = (const int*)d_in[2];
    const int*   gid   = (const int*)d_in[3];
    const float* W0    = (const float*)d_in[4];
    const float* al0   = (const float*)d_in[5];
    const float* ar0   = (const float*)d_in[6];
    const float* b0    = (const float*)d_in[7];
    const float* W1    = (const float*)d_in[8];
    const float* al1   = (const float*)d_in[9];
    const float* ar1   = (const float*)d_in[10];
    const float* b1    = (const float*)d_in[11];
    const float* W2    = (const float*)d_in[12];
    const float* al2   = (const float*)d_in[13];
    const float* ar2   = (const float*)d_in[14];
    const float* b2    = (const float*)d_in[15];
    const float* g0    = (const float*)d_in[16];
    const float* beta0 = (const float*)d_in[17];
    const float* g1    = (const float*)d_in[18];
    const float* beta1 = (const float*)d_in[19];
    const float* Wc    = (const float*)d_in[20];
    const float* bc    = (const float*)d_in[21];

    ushort* featbf  = (ushort*)d_ws;                          // [N,128] bf16 GEMM out
    ushort* xnext   = featbf + (size_t)NNODES * 128;          // [N,128] bf16 gather out / GEMM in
    float*  el      = (float*)(xnext + (size_t)NNODES * 128); // [N,4]
    float*  er      = el + (size_t)NNODES * 4;                // [N,4]
    float*  pooled  = er + (size_t)NNODES * 4;                // [500,32]
    float*  bnacc   = pooled + NGRAPHS * 32;                  // [512]: gsumA,gsumsqA,gsumB,gsumsqB
    float*  gsumA   = bnacc;
    float*  gsumsqA = bnacc + 128;
    float*  gsumB   = bnacc + 256;
    float*  gsumsqB = bnacc + 384;
    int* rowptr  = (int*)(bnacc + 512);                       // [N+1]
    int* csr_src = rowptr + NNODES + 1;                       // [E]
    uint* bucket = (uint*)(csr_src + NEDGES);                 // [E]
    int* rhist   = (int*)(bucket + NEDGES);                   // [NRANGE]
    int* rbase   = rhist + NRANGE;                            // [NRANGE+1]
    int* rcursor = rbase + NRANGE + 1;                        // [NRANGE]
    ushort* Wt0  = (ushort*)(rcursor + NRANGE);               // [128,128]
    ushort* Wt1  = Wt0 + 128 * 128;                           // [128,128]
    ushort* Wt2  = Wt1 + 128 * 128;                           // [32,128]

    const int T = 256;
    float* out = (float*)d_out;

    // ---- prep + pooled zero ----
    hipMemsetAsync(pooled, 0, (size_t)NGRAPHS * 32 * 4, stream);
    prep_kernel<<<144, T, 0, stream>>>(W0, W1, W2, Wt0, Wt1, Wt2, rhist, bnacc);

    // ---- bucketed CSR build ----
    range_hist_kernel<<<RH_NB, T, 0, stream>>>(edst, rhist);
    range_scan_kernel<<<1, T, 0, stream>>>(rhist, rbase, rcursor, rowptr);
    reorder_kernel<<<RH_NB, T, 0, stream>>>(esrc, edst, rcursor, bucket);
    range_csr_kernel<<<NRANGE, T, 0, stream>>>(rbase, bucket, rowptr, csr_src);

    const int GATHER4_BLOCKS = (NNODES + 3) / 4;          // one node per wave
    const int GATHER1_BLOCKS = (NNODES * 64 + T - 1) / T;
    const int GEMM128_BLOCKS = (NNODES + 63) / 64;
    const int GEMM32_BLOCKS  = (NNODES + 127) / 128;

    // ================= Layer 0 =================
    gemm_mfma_kernel<128, false><<<GEMM128_BLOCKS, T, 0, stream>>>(
        x, Wt0, nullptr, nullptr, nullptr, nullptr, al0, ar0, featbf, el, er, NNODES);
    gat_gather4_kernel<<<GATHER4_BLOCKS, T, 0, stream>>>(rowptr, csr_src, el, er, featbf, b0,
                                                         xnext, gsumA, gsumsqA);

    // ================= Layer 1 =================
    gemm_mfma_kernel<128, true><<<GEMM128_BLOCKS, T, 0, stream>>>(
        xnext, Wt1, gsumA, gsumsqA, g0, beta0, al1, ar1, featbf, el, er, NNODES);
    gat_gather4_kernel<<<GATHER4_BLOCKS, T, 0, stream>>>(rowptr, csr_src, el, er, featbf, b1,
                                                         xnext, gsumB, gsumsqB);

    // ================= Layer 2 (H=1, D=32) =================
    gemm_mfma_kernel<32, true><<<GEMM32_BLOCKS, T, 0, stream>>>(
        xnext, Wt2, gsumB, gsumsqB, g1, beta1, al2, ar2, featbf, el, er, NNODES);
    gat_gather1_kernel<<<GATHER1_BLOCKS, T, 0, stream>>>(rowptr, csr_src, el, er, featbf, b2,
                                                         gid, pooled);

    // ================= Classify =================
    classify_kernel<<<(NGRAPHS * 10 + T - 1) / T, T, 0, stream>>>(pooled, Wc, bc, out);
}

// Round 10
// 342.921 us; speedup vs baseline: 2.4651x; 2.4651x over previous
//
#include <hip/hip_runtime.h>
#include <math.h>

#define NNODES 50000
#define NEDGES 800000
#define NGRAPHS 500
#define NEG_SLOPE 0.2f
#define BN_EPS 1e-5f
#define NRANGE 196            // ceil(50000/256) node ranges of 256
#define RH_EPB 4096           // edges per block in range hist/reorder
#define RH_NB ((NEDGES + RH_EPB - 1) / RH_EPB)
#define MAXRE 5120            // LDS stage capacity per range
#define BN_NB 200
#define BN_RPB 250

typedef unsigned int uint;
typedef unsigned short ushort;
typedef __attribute__((ext_vector_type(8))) short bf16x8;
typedef __attribute__((ext_vector_type(4))) float f32x4;

// ---- bf16 helpers (storage-only bf16; math fp32 / MFMA fp32-acc) ----
__device__ __forceinline__ float bf2f(ushort u) { return __uint_as_float(((uint)u) << 16); }
__device__ __forceinline__ float bflo(uint u)   { return __uint_as_float(u << 16); }
__device__ __forceinline__ float bfhi(uint u)   { return __uint_as_float(u & 0xffff0000u); }
__device__ __forceinline__ ushort f2bf(float f) {
    uint u = __float_as_uint(f);
    u = (u + 0x7fffu + ((u >> 16) & 1u)) >> 16;   // RNE
    return (ushort)u;
}

// ---- prep: zero rhist, convert/transpose weights to bf16 ----
__global__ void prep_kernel(const float* __restrict__ W0, const float* __restrict__ W1,
                            const float* __restrict__ W2, ushort* __restrict__ Wt0,
                            ushort* __restrict__ Wt1, ushort* __restrict__ Wt2,
                            int* __restrict__ rhist) {
    int t = blockIdx.x * 256 + threadIdx.x;
    if (blockIdx.x == 0 && threadIdx.x < NRANGE) rhist[threadIdx.x] = 0;
    if (t < 16384) {                       // W0 [128][128]
        int k = t >> 7, m = t & 127;
        Wt0[m * 128 + k] = f2bf(W0[t]);
    } else if (t < 32768) {                // W1 [128][128]
        int i = t - 16384;
        int k = i >> 7, m = i & 127;
        Wt1[m * 128 + k] = f2bf(W1[i]);
    } else if (t < 36864) {                // W2 [128][32]
        int i = t - 32768;
        int k = i >> 5, m = i & 31;
        Wt2[m * 128 + k] = f2bf(W2[i]);
    }
}

// ==================== bucketed CSR build ====================
__global__ void range_hist_kernel(const int* __restrict__ dst, int* __restrict__ rhist) {
    __shared__ int cnt[NRANGE];
    for (int i = threadIdx.x; i < NRANGE; i += 256) cnt[i] = 0;
    __syncthreads();
    int base = blockIdx.x * RH_EPB;
    int end = base + RH_EPB; if (end > NEDGES) end = NEDGES;
    for (int i = base + threadIdx.x; i < end; i += 256) atomicAdd(&cnt[dst[i] >> 8], 1);
    __syncthreads();
    for (int i = threadIdx.x; i < NRANGE; i += 256)
        if (cnt[i]) atomicAdd(&rhist[i], cnt[i]);
}

__global__ void range_scan_kernel(const int* __restrict__ rhist, int* __restrict__ rbase,
                                  int* __restrict__ rcursor, int* __restrict__ rowptr) {
    __shared__ int ls[256];
    int t = threadIdx.x;
    ls[t] = (t < NRANGE) ? rhist[t] : 0;
    __syncthreads();
    for (int off = 1; off < 256; off <<= 1) {
        int u = (t >= off) ? ls[t - off] : 0;
        __syncthreads();
        ls[t] += u;
        __syncthreads();
    }
    if (t < NRANGE) {
        int b = (t == 0) ? 0 : ls[t - 1];
        rbase[t] = b;
        rcursor[t] = b;
    }
    if (t == 0) { rbase[NRANGE] = NEDGES; rowptr[NNODES] = NEDGES; }
}

__global__ void reorder_kernel(const int* __restrict__ src, const int* __restrict__ dst,
                               int* __restrict__ rcursor, uint* __restrict__ bucket) {
    __shared__ int cnt[NRANGE];
    __shared__ int bofs[NRANGE];
    for (int i = threadIdx.x; i < NRANGE; i += 256) cnt[i] = 0;
    __syncthreads();
    int base = blockIdx.x * RH_EPB;
    int end = base + RH_EPB; if (end > NEDGES) end = NEDGES;
    for (int i = base + threadIdx.x; i < end; i += 256) atomicAdd(&cnt[dst[i] >> 8], 1);
    __syncthreads();
    for (int i = threadIdx.x; i < NRANGE; i += 256) {
        int c = cnt[i];
        bofs[i] = c ? atomicAdd(&rcursor[i], c) : 0;
    }
    __syncthreads();
    for (int i = threadIdx.x; i < NRANGE; i += 256) cnt[i] = 0;
    __syncthreads();
    for (int i = base + threadIdx.x; i < end; i += 256) {
        int d = dst[i], r = d >> 8;
        int loc = atomicAdd(&cnt[r], 1);
        bucket[bofs[r] + loc] = (uint)src[i] | ((uint)(d & 255) << 16);
    }
}

__global__ __launch_bounds__(256) void range_csr_kernel(const int* __restrict__ rbase,
                                                        const uint* __restrict__ bucket,
                                                        int* __restrict__ rowptr,
                                                        int* __restrict__ csr_src) {
    __shared__ uint ebuf[MAXRE];
    __shared__ int deg[256], excl[256], cur[256];
    const int r = blockIdx.x;
    const int b0 = rbase[r];
    const int cnt = rbase[r + 1] - b0;
    const int t = threadIdx.x;
    deg[t] = 0; cur[t] = 0;
    __syncthreads();
    for (int i = t; i < cnt; i += 256) {
        uint e = bucket[b0 + i];
        ebuf[i] = e;
        atomicAdd(&deg[e >> 16], 1);
    }
    __syncthreads();
    excl[t] = deg[t];
    __syncthreads();
    for (int off = 1; off < 256; off <<= 1) {
        int u = (t >= off) ? excl[t - off] : 0;
        __syncthreads();
        excl[t] += u;
        __syncthreads();
    }
    int myExcl = (t == 0) ? 0 : excl[t - 1];
    __syncthreads();
    excl[t] = myExcl;
    __syncthreads();
    int node = r * 256 + t;
    if (node < NNODES) rowptr[node] = b0 + myExcl;
    for (int i = t; i < cnt; i += 256) {
        uint e = ebuf[i];
        int dl = e >> 16;
        int loc = atomicAdd(&cur[dl], 1);
        csr_src[b0 + excl[dl] + loc] = (int)(e & 0xffffu);
    }
}

// ==================== MFMA bf16 GEMM, fused BN/ReLU input + el/er epilogue ====================
// HASBN: X bf16, scale/shift precomputed by bn_finalize. !HASBN: X fp32.
template <int M, bool HASBN>
__global__ __launch_bounds__(256) void gemm_mfma_kernel(
        const void* __restrict__ Xv, const ushort* __restrict__ Wt,
        const float* __restrict__ scale, const float* __restrict__ shift,
        const float* __restrict__ al, const float* __restrict__ ar,
        ushort* __restrict__ Y, float* __restrict__ el, float* __restrict__ er, int N) {
    constexpr int H   = M / 32;
    constexpr int BR  = (M == 128) ? 64 : 128;
    constexpr int RT  = (M == 128) ? 4 : 2;
    constexpr int CT  = 2;
    constexpr int LDK = 136;
    __shared__ ushort xs[BR][LDK];
    __shared__ ushort ws[M][LDK];
    __shared__ float scs[128], shs[128];

    const int tid = threadIdx.x, wv = tid >> 6, lane = tid & 63;
    const int rowBase = blockIdx.x * BR;

    if (HASBN) {
        if (tid < 128) {
            scs[tid] = scale[tid];
            shs[tid] = shift[tid];
        }
        __syncthreads();
    }

    if (HASBN) {
        const ushort* X = (const ushort*)Xv;
        for (int i = tid; i < BR * 16; i += 256) {
            int rr = i >> 4, q = i & 15;
            int gr = rowBase + rr;
            uint4 u = make_uint4(0, 0, 0, 0);
            if (gr < N) u = *(const uint4*)(X + (size_t)gr * 128 + q * 8);
            uint arr[4] = {u.x, u.y, u.z, u.w};
            ushort* o = &xs[rr][q * 8];
#pragma unroll
            for (int j = 0; j < 4; ++j) {
                int c = q * 8 + j * 2;
                float lo = fmaxf(bflo(arr[j]) * scs[c] + shs[c], 0.f);
                float hi = fmaxf(bfhi(arr[j]) * scs[c + 1] + shs[c + 1], 0.f);
                o[j * 2]     = f2bf(lo);
                o[j * 2 + 1] = f2bf(hi);
            }
        }
    } else {
        const float* X = (const float*)Xv;
        for (int i = tid; i < BR * 32; i += 256) {
            int rr = i >> 5, c4 = i & 31;
            int gr = rowBase + rr;
            float4 v = make_float4(0.f, 0.f, 0.f, 0.f);
            if (gr < N) v = *(const float4*)(X + (size_t)gr * 128 + c4 * 4);
            ushort* o = &xs[rr][c4 * 4];
            o[0] = f2bf(v.x); o[1] = f2bf(v.y); o[2] = f2bf(v.z); o[3] = f2bf(v.w);
        }
    }
    for (int i = tid; i < M * 16; i += 256) {
        int rr = i >> 4, kc = (i & 15) * 8;
        *(uint4*)&ws[rr][kc] = *(const uint4*)(Wt + rr * 128 + kc);
    }
    __syncthreads();

    const int waveRow = (M == 128) ? 0 : (wv * 32);
    const int waveCol = (M == 128) ? (wv * 32) : 0;
    const int fr = lane & 15, quad = lane >> 4;

    f32x4 acc[RT][CT];
#pragma unroll
    for (int rt = 0; rt < RT; ++rt)
#pragma unroll
        for (int ct = 0; ct < CT; ++ct) acc[rt][ct] = (f32x4){0.f, 0.f, 0.f, 0.f};

#pragma unroll
    for (int ks = 0; ks < 4; ++ks) {
        const int kb = ks * 32 + quad * 8;
        bf16x8 a[RT], b[CT];
#pragma unroll
        for (int rt = 0; rt < RT; ++rt) a[rt] = *(const bf16x8*)&xs[waveRow + rt * 16 + fr][kb];
#pragma unroll
        for (int ct = 0; ct < CT; ++ct) b[ct] = *(const bf16x8*)&ws[waveCol + ct * 16 + fr][kb];
#pragma unroll
        for (int rt = 0; rt < RT; ++rt)
#pragma unroll
            for (int ct = 0; ct < CT; ++ct)
                acc[rt][ct] = __builtin_amdgcn_mfma_f32_16x16x32_bf16(a[rt], b[ct], acc[rt][ct], 0, 0, 0);
    }

#pragma unroll
    for (int rt = 0; rt < RT; ++rt)
#pragma unroll
        for (int ct = 0; ct < CT; ++ct)
#pragma unroll
            for (int rg = 0; rg < 4; ++rg) {
                int gr = rowBase + waveRow + rt * 16 + quad * 4 + rg;
                int gc = waveCol + ct * 16 + fr;
                if (gr < N) Y[(size_t)gr * M + gc] = f2bf(acc[rt][ct][rg]);
            }

    // fused el/er epilogue
    const float a0 = al[waveCol + fr],      a1 = al[waveCol + 16 + fr];
    const float g0 = ar[waveCol + fr],      g1 = ar[waveCol + 16 + fr];
    const int h = (M == 128) ? wv : 0;
#pragma unroll
    for (int rt = 0; rt < RT; ++rt)
#pragma unroll
        for (int rg = 0; rg < 4; ++rg) {
            float pe = acc[rt][0][rg] * a0 + acc[rt][1][rg] * a1;
            float pr = acc[rt][0][rg] * g0 + acc[rt][1][rg] * g1;
#pragma unroll
            for (int off = 1; off < 16; off <<= 1) {
                pe += __shfl_xor(pe, off);
                pr += __shfl_xor(pr, off);
            }
            int grow = rowBase + waveRow + rt * 16 + quad * 4 + rg;
            if (fr == 0 && grow < N) {
                el[grow * H + h] = pe;
                er[grow * H + h] = pr;
            }
        }
}

// ==================== gather H=4: one node/wave, bf16 out — NO atomics, NO LDS ====================
__global__ __launch_bounds__(256) void gat_gather4_kernel(
        const int* __restrict__ rowptr, const int* __restrict__ csr_src,
        const float* __restrict__ el, const float* __restrict__ er,
        const ushort* __restrict__ feat, const float* __restrict__ bias,
        ushort* __restrict__ xnext) {
    const int d = (blockIdx.x * blockDim.x + threadIdx.x) >> 6;
    const int lane = threadIdx.x & 63;
    if (d >= NNODES) return;
    const int h   = lane >> 4;
    const int k   = lane & 15;
    const int grp = lane & 48;
    const int c0  = lane * 2;
    const int r0 = rowptr[d];
    const int deg = rowptr[d + 1] - r0;
    const float erh = er[d * 4 + h];
    float dnm = 0.f, ax = 0.f, ay = 0.f;

    for (int j0 = 0; j0 < deg; j0 += 16) {
        int eidx = j0 + k;
        int s_e = 0;
        float ex = 0.f;
        if (eidx < deg) {
            s_e = csr_src[r0 + eidx];
            float v = el[s_e * 4 + h] + erh;
            v = v > 0.f ? v : NEG_SLOPE * v;
            ex = __expf(v);
        }
        dnm += ex;
        uint u[16];
#pragma unroll
        for (int jj = 0; jj < 16; ++jj) {
            int sj = __builtin_amdgcn_readlane(s_e, jj);
            u[jj] = *(const uint*)(feat + (size_t)sj * 128 + c0);
        }
#pragma unroll
        for (int jj = 0; jj < 16; ++jj) {
            float exj = __shfl(ex, grp + jj);
            ax = fmaf(exj, bflo(u[jj]), ax);
            ay = fmaf(exj, bfhi(u[jj]), ay);
        }
    }
#pragma unroll
    for (int off = 1; off < 16; off <<= 1) dnm += __shfl_xor(dnm, off);
    float inv = (dnm > 0.f) ? 1.f / dnm : 0.f;
    float vx = ax * inv + bias[c0];
    float vy = ay * inv + bias[c0 + 1];
    uint pk = ((uint)f2bf(vy) << 16) | (uint)f2bf(vx);
    *(uint*)(xnext + (size_t)d * 128 + c0) = pk;
}

// ---- BN stats from bf16 xnext: per-block partials (no atomics) ----
__global__ void bn_stats_kernel(const ushort* __restrict__ X, float* __restrict__ psum,
                                float* __restrict__ psumsq) {
    const uint* X32 = (const uint*)X;          // [N][64] packed col pairs
    int uc = threadIdx.x & 63;                 // uint col (cols 2uc, 2uc+1)
    int rq = threadIdx.x >> 6;                 // row quarter
    int r0 = blockIdx.x * BN_RPB;
    float s0 = 0.f, s1 = 0.f, ss0 = 0.f, ss1 = 0.f;
    for (int r = r0 + rq; r < r0 + BN_RPB; r += 4) {
        uint u = X32[(size_t)r * 64 + uc];
        float lo = bflo(u), hi = bfhi(u);
        s0 += lo; ss0 += lo * lo;
        s1 += hi; ss1 += hi * hi;
    }
    __shared__ float red[4][256], redsq[4][256];
    red[rq][uc * 2] = s0;      red[rq][uc * 2 + 1] = s1;
    redsq[rq][uc * 2] = ss0;   redsq[rq][uc * 2 + 1] = ss1;
    __syncthreads();
    int t = threadIdx.x;
    if (t < 128) {
        psum[blockIdx.x * 128 + t] = red[0][t] + red[1][t] + red[2][t] + red[3][t];
    } else {
        int c = t - 128;
        psumsq[blockIdx.x * 128 + c] = redsq[0][c] + redsq[1][c] + redsq[2][c] + redsq[3][c];
    }
}

// ---- reduce partials -> scale/shift ----
__global__ void bn_finalize_kernel(const float* __restrict__ psum, const float* __restrict__ psumsq,
                                   const float* __restrict__ g, const float* __restrict__ beta,
                                   float* __restrict__ scale, float* __restrict__ shift) {
    int c = threadIdx.x;   // 128 threads
    float s = 0.f, ss = 0.f;
    for (int b = 0; b < BN_NB; ++b) {
        s += psum[b * 128 + c];
        ss += psumsq[b * 128 + c];
    }
    const float inv = 1.f / NNODES;
    float mu = s * inv;
    float var = ss * inv - mu * mu;
    float sc = g[c] * rsqrtf(var + BN_EPS);
    scale[c] = sc;
    shift[c] = beta[c] - mu * sc;
}

// ==================== gather H=1 with fused graph pooling ====================
__global__ void gat_gather1_kernel(const int* __restrict__ rowptr, const int* __restrict__ csr_src,
                                   const float* __restrict__ el, const float* __restrict__ er,
                                   const ushort* __restrict__ feat, const float* __restrict__ bias,
                                   const int* __restrict__ gid, float* __restrict__ pooled) {
    int wave = (blockIdx.x * blockDim.x + threadIdx.x) >> 6;
    int lane = threadIdx.x & 63;
    if (wave >= NNODES) return;
    const int d = wave;
    const int r0 = rowptr[d];
    const int deg = rowptr[d + 1] - r0;
    const int half = lane >> 5;
    const int c    = lane & 31;
    const float erh = er[d];
    float dnm = 0.f, acc = 0.f;

    for (int j0 = 0; j0 < deg; j0 += 32) {
        int eidx = j0 + (lane & 31);
        int s_e = 0;
        float ex = 0.f;
        if (eidx < deg) {
            s_e = csr_src[r0 + eidx];
            float v = el[s_e] + erh;
            v = v > 0.f ? v : NEG_SLOPE * v;
            ex = __expf(v);
        }
        dnm += ex;
        ushort u[16];
#pragma unroll
        for (int jj = 0; jj < 16; ++jj) {
            int sj = __shfl(s_e, 2 * jj + half);
            u[jj] = feat[(size_t)sj * 32 + c];
        }
#pragma unroll
        for (int jj = 0; jj < 16; ++jj) {
            float exj = __shfl(ex, 2 * jj + half);
            acc = fmaf(exj, bf2f(u[jj]), acc);
        }
    }
#pragma unroll
    for (int off = 1; off < 32; off <<= 1) dnm += __shfl_xor(dnm, off);
    acc += __shfl_down(acc, 32);
    if (half == 0) {
        float inv = (dnm > 0.f) ? 1.f / dnm : 0.f;
        atomicAdd(&pooled[gid[d] * 32 + c], acc * inv + bias[c]);
    }
}

// ---- classifier ----
__global__ void classify_kernel(const float* __restrict__ pooled, const float* __restrict__ Wc,
                                const float* __restrict__ bc, float* __restrict__ out) {
    int t = blockIdx.x * blockDim.x + threadIdx.x;
    if (t >= NGRAPHS * 10) return;
    int gIdx = t / 10, j = t % 10;
    float s = bc[j];
#pragma unroll
    for (int c = 0; c < 32; ++c) s += pooled[gIdx * 32 + c] * Wc[c * 10 + j];
    out[t] = s;
}

extern "C" void kernel_launch(void* const* d_in, const int* in_sizes, int n_in,
                              void* d_out, int out_size, void* d_ws, size_t ws_size,
                              hipStream_t stream) {
    const float* x     = (const float*)d_in[0];
    const int*   esrc  = (const int*)d_in[1];
    const int*   edst  = (const int*)d_in[2];
    const int*   gid   = (const int*)d_in[3];
    const float* W0    = (const float*)d_in[4];
    const float* al0   = (const float*)d_in[5];
    const float* ar0   = (const float*)d_in[6];
    const float* b0    = (const float*)d_in[7];
    const float* W1    = (const float*)d_in[8];
    const float* al1   = (const float*)d_in[9];
    const float* ar1   = (const float*)d_in[10];
    const float* b1    = (const float*)d_in[11];
    const float* W2    = (const float*)d_in[12];
    const float* al2   = (const float*)d_in[13];
    const float* ar2   = (const float*)d_in[14];
    const float* b2    = (const float*)d_in[15];
    const float* g0    = (const float*)d_in[16];
    const float* beta0 = (const float*)d_in[17];
    const float* g1    = (const float*)d_in[18];
    const float* beta1 = (const float*)d_in[19];
    const float* Wc    = (const float*)d_in[20];
    const float* bc    = (const float*)d_in[21];

    ushort* featbf  = (ushort*)d_ws;                          // [N,128] bf16 GEMM out
    ushort* xnext   = featbf + (size_t)NNODES * 128;          // [N,128] bf16 gather out / GEMM in
    float*  el      = (float*)(xnext + (size_t)NNODES * 128); // [N,4]
    float*  er      = el + (size_t)NNODES * 4;                // [N,4]
    float*  pooled  = er + (size_t)NNODES * 4;                // [500,32]
    float*  psum    = pooled + NGRAPHS * 32;                  // [200,128]
    float*  psumsq  = psum + BN_NB * 128;                     // [200,128]
    float*  scale0  = psumsq + BN_NB * 128;                   // [128]
    float*  shift0  = scale0 + 128;                           // [128]
    float*  scale1  = shift0 + 128;                           // [128]
    float*  shift1  = scale1 + 128;                           // [128]
    int* rowptr  = (int*)(shift1 + 128);                      // [N+1]
    int* csr_src = rowptr + NNODES + 1;                       // [E]
    uint* bucket = (uint*)(csr_src + NEDGES);                 // [E]
    int* rhist   = (int*)(bucket + NEDGES);                   // [NRANGE]
    int* rbase   = rhist + NRANGE;                            // [NRANGE+1]
    int* rcursor = rbase + NRANGE + 1;                        // [NRANGE]
    ushort* Wt0  = (ushort*)(rcursor + NRANGE);               // [128,128]
    ushort* Wt1  = Wt0 + 128 * 128;                           // [128,128]
    ushort* Wt2  = Wt1 + 128 * 128;                           // [32,128]

    const int T = 256;
    float* out = (float*)d_out;

    // ---- prep + pooled zero ----
    hipMemsetAsync(pooled, 0, (size_t)NGRAPHS * 32 * 4, stream);
    prep_kernel<<<144, T, 0, stream>>>(W0, W1, W2, Wt0, Wt1, Wt2, rhist);

    // ---- bucketed CSR build ----
    range_hist_kernel<<<RH_NB, T, 0, stream>>>(edst, rhist);
    range_scan_kernel<<<1, T, 0, stream>>>(rhist, rbase, rcursor, rowptr);
    reorder_kernel<<<RH_NB, T, 0, stream>>>(esrc, edst, rcursor, bucket);
    range_csr_kernel<<<NRANGE, T, 0, stream>>>(rbase, bucket, rowptr, csr_src);

    const int GATHER4_BLOCKS = (NNODES * 64 + T - 1) / T;     // one node per wave
    const int GATHER1_BLOCKS = (NNODES * 64 + T - 1) / T;
    const int GEMM128_BLOCKS = (NNODES + 63) / 64;
    const int GEMM32_BLOCKS  = (NNODES + 127) / 128;

    // ================= Layer 0 =================
    gemm_mfma_kernel<128, false><<<GEMM128_BLOCKS, T, 0, stream>>>(
        x, Wt0, nullptr, nullptr, al0, ar0, featbf, el, er, NNODES);
    gat_gather4_kernel<<<GATHER4_BLOCKS, T, 0, stream>>>(rowptr, csr_src, el, er, featbf, b0, xnext);
    bn_stats_kernel<<<BN_NB, T, 0, stream>>>(xnext, psum, psumsq);
    bn_finalize_kernel<<<1, 128, 0, stream>>>(psum, psumsq, g0, beta0, scale0, shift0);

    // ================= Layer 1 =================
    gemm_mfma_kernel<128, true><<<GEMM128_BLOCKS, T, 0, stream>>>(
        xnext, Wt1, scale0, shift0, al1, ar1, featbf, el, er, NNODES);
    gat_gather4_kernel<<<GATHER4_BLOCKS, T, 0, stream>>>(rowptr, csr_src, el, er, featbf, b1, xnext);
    bn_stats_kernel<<<BN_NB, T, 0, stream>>>(xnext, psum, psumsq);
    bn_finalize_kernel<<<1, 128, 0, stream>>>(psum, psumsq, g1, beta1, scale1, shift1);

    // ================= Layer 2 (H=1, D=32) =================
    gemm_mfma_kernel<32, true><<<GEMM32_BLOCKS, T, 0, stream>>>(
        xnext, Wt2, scale1, shift1, al2, ar2, featbf, el, er, NNODES);
    gat_gather1_kernel<<<GATHER1_BLOCKS, T, 0, stream>>>(rowptr, csr_src, el, er, featbf, b2,
                                                         gid, pooled);

    // ================= Classify =================
    classify_kernel<<<(NGRAPHS * 10 + T - 1) / T, T, 0, stream>>>(pooled, Wc, bc, out);
}